// Round 1
// baseline (6744.685 us; speedup 1.0000x reference)
//
#include <hip/hip_runtime.h>
#include <stdint.h>

#define ND 1024
#define NF 4096
#define NE 8
#define NT 16384
#define NTILES 264
#define OUT_ELEMS 16777216UL

typedef unsigned short u16;
typedef unsigned int u32;
typedef __attribute__((ext_vector_type(8))) short bf16x8;
typedef __attribute__((ext_vector_type(16))) float f32x16;

__device__ __forceinline__ u16 f2bf(float f){
  u32 u = __float_as_uint(f);
  u += 0x7fffu + ((u >> 16) & 1u);
  return (u16)(u >> 16);
}
__device__ __forceinline__ float bf2f(u16 h){ return __uint_as_float(((u32)h) << 16); }

__device__ __forceinline__ f32x16 MFMA(bf16x8 a, bf16x8 b, f32x16 c){
  return __builtin_amdgcn_mfma_f32_32x32x16_bf16(a, b, c, 0, 0, 0);
}

#define GLD_LDS(lds, g) __builtin_amdgcn_global_load_lds( \
    (const __attribute__((address_space(1))) u32*)(g), \
    (__attribute__((address_space(3))) u32*)(lds), 16, 0, 0)

// ---------------- split fp32 -> bf16 hi/lo ----------------
__global__ __launch_bounds__(256) void k_split_plain(const float* __restrict__ s,
    u16* __restrict__ hi, u16* __restrict__ lo, int n){
  int i = (blockIdx.x * 256 + threadIdx.x) * 4;
  if (i >= n) return;
  float4 v = *(const float4*)(s + i);
  u16 h0=f2bf(v.x), h1=f2bf(v.y), h2=f2bf(v.z), h3=f2bf(v.w);
  u16 l0=f2bf(v.x-bf2f(h0)), l1=f2bf(v.y-bf2f(h1)), l2=f2bf(v.z-bf2f(h2)), l3=f2bf(v.w-bf2f(h3));
  uint2 H, L;
  H.x = (u32)h0 | ((u32)h1<<16); H.y = (u32)h2 | ((u32)h3<<16);
  L.x = (u32)l0 | ((u32)l1<<16); L.y = (u32)l2 | ((u32)l3<<16);
  *(uint2*)(hi + i) = H; *(uint2*)(lo + i) = L;
}

// pre-swizzled split: within each 16-elem chunk of a row, the two 8-elem
// granules are swapped when (row&1)==1, so global_load_lds (linear dest)
// produces the bank-conflict-free LDS layout the GEMMs read.
__global__ __launch_bounds__(256) void k_split_swz(const float* __restrict__ s,
    u16* __restrict__ hi, u16* __restrict__ lo, int n, int L){
  int i = (blockIdx.x * 256 + threadIdx.x) * 4;
  if (i >= n) return;
  float4 v = *(const float4*)(s + i);
  u16 h0=f2bf(v.x), h1=f2bf(v.y), h2=f2bf(v.z), h3=f2bf(v.w);
  u16 l0=f2bf(v.x-bf2f(h0)), l1=f2bf(v.y-bf2f(h1)), l2=f2bf(v.z-bf2f(h2)), l3=f2bf(v.w-bf2f(h3));
  uint2 H, Lo;
  H.x = (u32)h0 | ((u32)h1<<16); H.y = (u32)h2 | ((u32)h3<<16);
  Lo.x = (u32)l0 | ((u32)l1<<16); Lo.y = (u32)l2 | ((u32)l3<<16);
  int row = i >> L;
  int col = i & ((1 << L) - 1);
  int g = (col >> 3) & 1;
  int cs = (col & ~15) | ((g ^ (row & 1)) << 3) | (col & 7);
  size_t d = ((size_t)row << L) + (size_t)cs;
  *(uint2*)(hi + d) = H; *(uint2*)(lo + d) = Lo;
}

// ---------------- router (fp32 exact) ----------------
__global__ __launch_bounds__(256) void k_router(const float* __restrict__ x, const float* __restrict__ gw,
    float* __restrict__ probs, int* __restrict__ topidx, float* __restrict__ topw, int* __restrict__ counts){
  __shared__ float gs[NE * ND];
  int tid = threadIdx.x;
  for (int i = tid * 4; i < NE * ND; i += 1024) *(float4*)(gs + i) = *(const float4*)(gw + i);
  __syncthreads();
  int lane = tid & 63, wv = tid >> 6;
  int t = blockIdx.x * 4 + wv;
  const float* xr = x + (size_t)t * ND;
  float xv[16];
  #pragma unroll
  for (int i = 0; i < 16; i++) xv[i] = xr[lane + 64 * i];
  float lg[8];
  #pragma unroll
  for (int e = 0; e < 8; e++){
    float p = 0.f;
    #pragma unroll
    for (int i = 0; i < 16; i++) p += xv[i] * gs[e * ND + lane + 64 * i];
    #pragma unroll
    for (int off = 1; off < 64; off <<= 1) p += __shfl_xor(p, off, 64);
    lg[e] = p;
  }
  if (lane == 0){
    float m = lg[0];
    #pragma unroll
    for (int e = 1; e < 8; e++) m = fmaxf(m, lg[e]);
    float pr[8], ssum = 0.f;
    #pragma unroll
    for (int e = 0; e < 8; e++){ pr[e] = __expf(lg[e] - m); ssum += pr[e]; }
    float inv = 1.f / ssum;
    #pragma unroll
    for (int e = 0; e < 8; e++){ pr[e] *= inv; probs[(size_t)t * 8 + e] = pr[e]; }
    int i1 = 0;
    #pragma unroll
    for (int e = 1; e < 8; e++) if (lg[e] > lg[i1]) i1 = e;
    int i2 = (i1 == 0) ? 1 : 0;
    #pragma unroll
    for (int e = 0; e < 8; e++) if (e != i1 && lg[e] > lg[i2]) i2 = e;
    float wsum = pr[i1] + pr[i2];
    topidx[t * 2 + 0] = i1; topw[t * 2 + 0] = pr[i1] / wsum;
    topidx[t * 2 + 1] = i2; topw[t * 2 + 1] = pr[i2] / wsum;
    atomicAdd(&counts[i1], 1); atomicAdd(&counts[i2], 1);
  }
}

__global__ void k_fill(int* __restrict__ ltok){
  ltok[blockIdx.x * 256 + threadIdx.x] = -1;
}

// ctrl: [0..7]=counts [8..15]=cursors [16..24]=padded_off [32..32+NTILES)=tile_expert
__global__ __launch_bounds__(256) void k_offsets(int* __restrict__ ctrl){
  __shared__ int po[9];
  if (threadIdx.x == 0){
    int off = 0;
    #pragma unroll
    for (int e = 0; e < 8; e++){
      ctrl[16 + e] = off; po[e] = off;
      off += (ctrl[e] + 127) & ~127;
    }
    ctrl[24] = off; po[8] = off;
  }
  __syncthreads();
  for (int i = threadIdx.x; i < NTILES; i += 256){
    int rowb = i * 128;
    int e = -1;
    #pragma unroll
    for (int k = 0; k < 8; k++) if (rowb >= po[k] && rowb < po[k + 1]) e = k;
    ctrl[32 + i] = e;
  }
}

__global__ __launch_bounds__(256) void k_scatter(const int* __restrict__ topidx, const float* __restrict__ topw,
    int* __restrict__ ctrl, int* __restrict__ ltok, float* __restrict__ lwv){
  int t = blockIdx.x * 256 + threadIdx.x;
  #pragma unroll
  for (int k = 0; k < 2; k++){
    int e = topidx[t * 2 + k];
    int pos = atomicAdd(&ctrl[8 + e], 1);
    int idx = ctrl[16 + e] + pos;
    ltok[idx] = t; lwv[idx] = topw[t * 2 + k];
  }
}

// ---------------- C1: H = silu(X·W1^T) * (X·W3^T), bf16x3 MFMA ----------------
// block 256 thr (4 waves, 2x2), block tile 128(m) x 128(f), BK=16
__global__ __launch_bounds__(256, 2) void k_mlp1(
    const u16* __restrict__ xh, const u16* __restrict__ xl,
    const u16* __restrict__ w1h, const u16* __restrict__ w1l,
    const u16* __restrict__ w3h, const u16* __restrict__ w3l,
    const int* __restrict__ ltok, const int* __restrict__ tile_expert,
    u16* __restrict__ Hh, u16* __restrict__ Hl, int tile0)
{
  const int bx = blockIdx.x;
  const int e = tile_expert[tile0 + bx];
  if (e < 0) return;
  const int tid = threadIdx.x;
  const int lane = tid & 63, wid = tid >> 6;
  const int wm = wid >> 1, wn = wid & 1;
  const int r = lane & 31, half = lane >> 5;
  const int f0 = blockIdx.y * 128;

  __shared__ alignas(16) u16 sA[2][2][128 * 16];
  __shared__ alignas(16) u16 sB[2][4][128 * 16];
  __shared__ int sm_tok[128];

  if (tid < 128) sm_tok[tid] = ltok[(tile0 + bx) * 128 + tid];
  __syncthreads();

  // A reg-stage map: thread -> (row, granule)
  const int arow = tid >> 1, ag = tid & 1;
  int tokA = sm_tok[arow]; if (tokA < 0) tokA = 0;
  const size_t a_src = (size_t)tokA * ND + (size_t)(ag * 8);
  const int a_dst = arow * 32 + ((ag ^ (arow & 1)) << 4);

  // B DMA map (per-lane global src, wave-uniform LDS base)
  const int bgi = wid * 64 + lane;
  const int brow = bgi >> 1, bg = bgi & 1;
  const size_t b_src = ((size_t)e * NF + (size_t)(f0 + brow)) * ND + (size_t)(bg * 8);
  const int b_dstw = wid * 1024;

  uint4 curH, curL, nxtH, nxtL;
  curH = *(const uint4*)(xh + a_src);
  curL = *(const uint4*)(xl + a_src);
  GLD_LDS((char*)&sB[0][0][0] + b_dstw, w1h + b_src);
  GLD_LDS((char*)&sB[0][1][0] + b_dstw, w1l + b_src);
  GLD_LDS((char*)&sB[0][2][0] + b_dstw, w3h + b_src);
  GLD_LDS((char*)&sB[0][3][0] + b_dstw, w3l + b_src);
  *(uint4*)((char*)&sA[0][0][0] + a_dst) = curH;
  *(uint4*)((char*)&sA[0][1][0] + a_dst) = curL;
  nxtH = *(const uint4*)(xh + a_src + 16);
  nxtL = *(const uint4*)(xl + a_src + 16);
  __syncthreads();

  f32x16 acc1[2][2], acc3[2][2];
  #pragma unroll
  for (int p = 0; p < 2; p++)
    #pragma unroll
    for (int q = 0; q < 2; q++)
      #pragma unroll
      for (int j = 0; j < 16; j++){ acc1[p][q][j] = 0.f; acc3[p][q][j] = 0.f; }

  int cur = 0;
  const int NK = ND / 16;
  for (int kt = 0; kt < NK; ++kt){
    const int nxt = cur ^ 1;
    if (kt + 1 < NK){
      curH = nxtH; curL = nxtL;
      *(uint4*)((char*)&sA[nxt][0][0] + a_dst) = curH;
      *(uint4*)((char*)&sA[nxt][1][0] + a_dst) = curL;
      const size_t bo = b_src + (size_t)(kt + 1) * 16;
      GLD_LDS((char*)&sB[nxt][0][0] + b_dstw, w1h + bo);
      GLD_LDS((char*)&sB[nxt][1][0] + b_dstw, w1l + bo);
      GLD_LDS((char*)&sB[nxt][2][0] + b_dstw, w3h + bo);
      GLD_LDS((char*)&sB[nxt][3][0] + b_dstw, w3l + bo);
      const int kt2 = (kt + 2 < NK) ? kt + 2 : kt + 1;
      nxtH = *(const uint4*)(xh + a_src + (size_t)kt2 * 16);
      nxtL = *(const uint4*)(xl + a_src + (size_t)kt2 * 16);
    }
    const char* Ah  = (const char*)&sA[cur][0][0];
    const char* Al  = (const char*)&sA[cur][1][0];
    const char* B1H = (const char*)&sB[cur][0][0];
    const char* B1L = (const char*)&sB[cur][1][0];
    const char* B3H = (const char*)&sB[cur][2][0];
    const char* B3L = (const char*)&sB[cur][3][0];
    bf16x8 a_h[2], a_l[2], b1_h[2], b1_l[2], b3_h[2], b3_l[2];
    #pragma unroll
    for (int p = 0; p < 2; p++){
      const int row = wm * 64 + p * 32 + r;
      const int byo = row * 32 + ((half ^ (row & 1)) << 4);
      a_h[p] = *(const bf16x8*)(Ah + byo);
      a_l[p] = *(const bf16x8*)(Al + byo);
    }
    #pragma unroll
    for (int q = 0; q < 2; q++){
      const int row = wn * 64 + q * 32 + r;
      const int byo = row * 32 + ((half ^ (row & 1)) << 4);
      b1_h[q] = *(const bf16x8*)(B1H + byo);
      b1_l[q] = *(const bf16x8*)(B1L + byo);
      b3_h[q] = *(const bf16x8*)(B3H + byo);
      b3_l[q] = *(const bf16x8*)(B3L + byo);
    }
    #pragma unroll
    for (int p = 0; p < 2; p++)
      #pragma unroll
      for (int q = 0; q < 2; q++){
        acc1[p][q] = MFMA(a_h[p], b1_h[q], acc1[p][q]);
        acc1[p][q] = MFMA(a_l[p], b1_h[q], acc1[p][q]);
        acc1[p][q] = MFMA(a_h[p], b1_l[q], acc1[p][q]);
        acc3[p][q] = MFMA(a_h[p], b3_h[q], acc3[p][q]);
        acc3[p][q] = MFMA(a_l[p], b3_h[q], acc3[p][q]);
        acc3[p][q] = MFMA(a_h[p], b3_l[q], acc3[p][q]);
      }
    __syncthreads();
    cur = nxt;
  }

  // epilogue: silu(s1)*s3 -> bf16 hi/lo, stored pre-swizzled for C2 DMA
  const int hb = bx * 128;
  #pragma unroll
  for (int p = 0; p < 2; p++)
    #pragma unroll
    for (int q = 0; q < 2; q++)
      #pragma unroll
      for (int j = 0; j < 16; j++){
        const int rl = wm * 64 + p * 32 + (j & 3) + 8 * (j >> 2) + 4 * half;
        const int fc = f0 + wn * 64 + q * 32 + r;
        const float s1 = acc1[p][q][j];
        const float s3 = acc3[p][q][j];
        const float h = s1 * (1.f / (1.f + __expf(-s1))) * s3;
        const u16 hh = f2bf(h);
        const u16 hl = f2bf(h - bf2f(hh));
        const int fs = (fc & ~15) | ((((fc >> 3) & 1) ^ (rl & 1)) << 3) | (fc & 7);
        const size_t o = (size_t)(hb + rl) * NF + (size_t)fs;
        Hh[o] = hh; Hl[o] = hl;
      }
}

// ---------------- C2: out += w * (H · W2^T), bf16x3 MFMA ----------------
// block 128 thr (2 waves on m), block tile 128(m) x 128(d), BK=16
__global__ __launch_bounds__(128, 2) void k_mlp2(
    const u16* __restrict__ Hh, const u16* __restrict__ Hl,
    const u16* __restrict__ w2h, const u16* __restrict__ w2l,
    const int* __restrict__ ltok, const float* __restrict__ lw,
    const int* __restrict__ tile_expert,
    float* __restrict__ out, int tile0)
{
  const int bx = blockIdx.x;
  const int e = tile_expert[tile0 + bx];
  if (e < 0) return;
  const int tid = threadIdx.x;
  const int lane = tid & 63, wid = tid >> 6;
  const int r = lane & 31, half = lane >> 5;
  const int d0 = blockIdx.y * 128;
  const int hb = bx * 128;

  __shared__ alignas(16) u16 sA[2][2][128 * 16];
  __shared__ alignas(16) u16 sB[2][2][128 * 16];
  __shared__ int sm_tok[128];
  __shared__ float sm_wt[128];

  if (tid < 128){
    sm_tok[tid] = ltok[(tile0 + bx) * 128 + tid];
    sm_wt[tid]  = lw[(tile0 + bx) * 128 + tid];
  }

  const int gi0 = wid * 128 + lane;
  const int row0 = gi0 >> 1, g0 = gi0 & 1;
  const int gi1 = gi0 + 64;
  const int row1 = gi1 >> 1, g1 = gi1 & 1;
  const size_t aoff0 = (size_t)(hb + row0) * NF + (size_t)(g0 * 8);
  const size_t aoff1 = (size_t)(hb + row1) * NF + (size_t)(g1 * 8);
  const size_t boff0 = ((size_t)e * ND + (size_t)(d0 + row0)) * NF + (size_t)(g0 * 8);
  const size_t boff1 = ((size_t)e * ND + (size_t)(d0 + row1)) * NF + (size_t)(g1 * 8);
  const int dst0 = wid * 2048;
  const int dst1 = wid * 2048 + 1024;

  GLD_LDS((char*)&sA[0][0][0] + dst0, Hh + aoff0);
  GLD_LDS((char*)&sA[0][0][0] + dst1, Hh + aoff1);
  GLD_LDS((char*)&sA[0][1][0] + dst0, Hl + aoff0);
  GLD_LDS((char*)&sA[0][1][0] + dst1, Hl + aoff1);
  GLD_LDS((char*)&sB[0][0][0] + dst0, w2h + boff0);
  GLD_LDS((char*)&sB[0][0][0] + dst1, w2h + boff1);
  GLD_LDS((char*)&sB[0][1][0] + dst0, w2l + boff0);
  GLD_LDS((char*)&sB[0][1][0] + dst1, w2l + boff1);
  __syncthreads();

  f32x16 acc[2][4];
  #pragma unroll
  for (int p = 0; p < 2; p++)
    #pragma unroll
    for (int q = 0; q < 4; q++)
      #pragma unroll
      for (int j = 0; j < 16; j++) acc[p][q][j] = 0.f;

  int cur = 0;
  const int NK = NF / 16;
  for (int kt = 0; kt < NK; ++kt){
    const int nxt = cur ^ 1;
    if (kt + 1 < NK){
      const size_t k16 = (size_t)(kt + 1) * 16;
      GLD_LDS((char*)&sA[nxt][0][0] + dst0, Hh + aoff0 + k16);
      GLD_LDS((char*)&sA[nxt][0][0] + dst1, Hh + aoff1 + k16);
      GLD_LDS((char*)&sA[nxt][1][0] + dst0, Hl + aoff0 + k16);
      GLD_LDS((char*)&sA[nxt][1][0] + dst1, Hl + aoff1 + k16);
      GLD_LDS((char*)&sB[nxt][0][0] + dst0, w2h + boff0 + k16);
      GLD_LDS((char*)&sB[nxt][0][0] + dst1, w2h + boff1 + k16);
      GLD_LDS((char*)&sB[nxt][1][0] + dst0, w2l + boff0 + k16);
      GLD_LDS((char*)&sB[nxt][1][0] + dst1, w2l + boff1 + k16);
    }
    const char* Ah = (const char*)&sA[cur][0][0];
    const char* Al = (const char*)&sA[cur][1][0];
    const char* Bh = (const char*)&sB[cur][0][0];
    const char* Bl = (const char*)&sB[cur][1][0];
    bf16x8 a_h[2], a_l[2], b_h[4], b_l[4];
    #pragma unroll
    for (int p = 0; p < 2; p++){
      const int row = wid * 64 + p * 32 + r;
      const int byo = row * 32 + ((half ^ (row & 1)) << 4);
      a_h[p] = *(const bf16x8*)(Ah + byo);
      a_l[p] = *(const bf16x8*)(Al + byo);
    }
    #pragma unroll
    for (int q = 0; q < 4; q++){
      const int row = q * 32 + r;
      const int byo = row * 32 + ((half ^ (row & 1)) << 4);
      b_h[q] = *(const bf16x8*)(Bh + byo);
      b_l[q] = *(const bf16x8*)(Bl + byo);
    }
    #pragma unroll
    for (int p = 0; p < 2; p++)
      #pragma unroll
      for (int q = 0; q < 4; q++){
        acc[p][q] = MFMA(a_h[p], b_h[q], acc[p][q]);
        acc[p][q] = MFMA(a_l[p], b_h[q], acc[p][q]);
        acc[p][q] = MFMA(a_h[p], b_l[q], acc[p][q]);
      }
    __syncthreads();
    cur = nxt;
  }

  #pragma unroll
  for (int p = 0; p < 2; p++)
    #pragma unroll
    for (int q = 0; q < 4; q++)
      #pragma unroll
      for (int j = 0; j < 16; j++){
        const int rl = wid * 64 + p * 32 + (j & 3) + 8 * (j >> 2) + 4 * half;
        const int tok = sm_tok[rl];
        if (tok >= 0){
          const int d = d0 + q * 32 + r;
          atomicAdd(out + (size_t)tok * ND + d, sm_wt[rl] * acc[p][q][j]);
        }
      }
}

// ---------------- host ----------------
extern "C" void kernel_launch(void* const* d_in, const int* in_sizes, int n_in,
                              void* d_out, int out_size, void* d_ws, size_t ws_size,
                              hipStream_t stream)
{
  (void)in_sizes; (void)n_in;
  const float* x  = (const float*)d_in[0];
  const float* gw = (const float*)d_in[1];
  const float* w1 = (const float*)d_in[2];
  const float* w3 = (const float*)d_in[3];
  const float* w2 = (const float*)d_in[4];
  float* out = (float*)d_out;
  char* ws = (char*)d_ws;

  size_t o = 0;
  int* ctrl = (int*)ws;                         o += 4096;
  int* topidx = (int*)(ws + o);                 o += (size_t)NT * 2 * 4;
  float* topw = (float*)(ws + o);               o += (size_t)NT * 2 * 4;
  int* ltok = (int*)(ws + o);                   o += (size_t)NTILES * 128 * 4;
  float* lwv = (float*)(ws + o);                o += (size_t)NTILES * 128 * 4;
  o = (o + 1023) & ~(size_t)1023;
  u16* xh = (u16*)(ws + o);  o += (size_t)NT * ND * 2;
  u16* xl = (u16*)(ws + o);  o += (size_t)NT * ND * 2;
  u16* w1h = (u16*)(ws + o); o += (size_t)NE * NF * ND * 2;
  u16* w1l = (u16*)(ws + o); o += (size_t)NE * NF * ND * 2;
  u16* w3h = (u16*)(ws + o); o += (size_t)NE * NF * ND * 2;
  u16* w3l = (u16*)(ws + o); o += (size_t)NE * NF * ND * 2;
  u16* w2h = (u16*)(ws + o); o += (size_t)NE * ND * NF * 2;
  u16* w2l = (u16*)(ws + o); o += (size_t)NE * ND * NF * 2;

  size_t avail = (ws_size > o) ? (ws_size - o) : 0;
  int tiles_cap = (int)(avail / ((size_t)128 * NF * 2 * 2));
  if (tiles_cap < 1) tiles_cap = 1;
  int tps = (tiles_cap < NTILES) ? tiles_cap : NTILES;
  int nslabs = (NTILES + tps - 1) / tps;
  u16* Hh = (u16*)(ws + o);
  u16* Hl = Hh + (size_t)tps * 128 * NF;

  hipMemsetAsync(d_out, 0, (size_t)out_size * 4, stream);
  hipMemsetAsync(ctrl, 0, 4096, stream);

  const int nx = NT * ND;
  const int nw = NE * NF * ND;
  k_split_plain<<<nx / 1024, 256, 0, stream>>>(x, xh, xl, nx);
  k_split_swz<<<nw / 1024, 256, 0, stream>>>(w1, w1h, w1l, nw, 10);
  k_split_swz<<<nw / 1024, 256, 0, stream>>>(w3, w3h, w3l, nw, 10);
  k_split_swz<<<nw / 1024, 256, 0, stream>>>(w2, w2h, w2l, nw, 12);
  k_router<<<NT / 4, 256, 0, stream>>>(x, gw, out + OUT_ELEMS, topidx, topw, ctrl);
  k_fill<<<(NTILES * 128) / 256, 256, 0, stream>>>(ltok);
  k_offsets<<<1, 256, 0, stream>>>(ctrl);
  k_scatter<<<NT / 256, 256, 0, stream>>>(topidx, topw, ctrl, ltok, lwv);

  for (int s = 0; s < nslabs; ++s){
    int tile0 = s * tps;
    int nt = NTILES - tile0; if (nt > tps) nt = tps;
    k_mlp1<<<dim3(nt, NF / 128), 256, 0, stream>>>(xh, xl, w1h, w1l, w3h, w3l,
                                                   ltok, ctrl + 32, Hh, Hl, tile0);
    k_mlp2<<<dim3(nt, ND / 128), 128, 0, stream>>>(Hh, Hl, w2h, w2l,
                                                   ltok, lwv, ctrl + 32, out, tile0);
  }
}

// Round 3
// 2934.822 us; speedup vs baseline: 2.2982x; 2.2982x over previous
//
#include <hip/hip_runtime.h>
#include <stdint.h>

#define ND 1024
#define NF 4096
#define NE 8
#define NT 16384
#define NTILES 264
#define OUT_ELEMS 16777216UL
#define BK 32

typedef unsigned short u16;
typedef unsigned int u32;
typedef _Float16 f16;
typedef __attribute__((ext_vector_type(8))) _Float16 f16x8;
typedef __attribute__((ext_vector_type(16))) float f32x16;

__device__ __forceinline__ f32x16 MFMA(f16x8 a, f16x8 b, f32x16 c){
  return __builtin_amdgcn_mfma_f32_32x32x16_f16(a, b, c, 0, 0, 0);
}

__device__ __forceinline__ u16 f2h_bits(float v){
  f16 h = (f16)v;
  return __builtin_bit_cast(u16, h);
}
__device__ __forceinline__ float h2f(u16 b){
  return (float)__builtin_bit_cast(f16, b);
}

// XOR-fold slot swizzle: bijective involution within each 64-slot (1KB) band.
// Slot S = row*granules_per_row + g ; phys = S ^ ((S>>3)&7).
// Makes ds_read_b128 column-slice reads hit every bank-group exactly 4x per
// 32-lane phase (the 1KB/128B floor), for both 2- and 4-granule rows.
__device__ __forceinline__ int swz(int S){ return S ^ ((S >> 3) & 7); }

#define GLD_LDS(lds, g) __builtin_amdgcn_global_load_lds( \
    (const __attribute__((address_space(1))) u32*)(g), \
    (__attribute__((address_space(3))) u32*)(lds), 16, 0, 0)

// ---------------- fp32 -> fp16 hi/lo split (x) ----------------
__global__ __launch_bounds__(256) void k_split_x(const float* __restrict__ s,
    u16* __restrict__ hi, u16* __restrict__ lo, int n){
  int i = (blockIdx.x * 256 + threadIdx.x) * 4;
  if (i >= n) return;
  float4 v = *(const float4*)(s + i);
  u16 h[4], l[4];
  float vv[4] = {v.x, v.y, v.z, v.w};
  #pragma unroll
  for (int j = 0; j < 4; j++){
    h[j] = f2h_bits(vv[j]);
    l[j] = f2h_bits(vv[j] - h2f(h[j]));
  }
  uint2 H, L;
  H.x = (u32)h[0] | ((u32)h[1] << 16); H.y = (u32)h[2] | ((u32)h[3] << 16);
  L.x = (u32)l[0] | ((u32)l[1] << 16); L.y = (u32)l[2] | ((u32)l[3] << 16);
  *(uint2*)(hi + i) = H; *(uint2*)(lo + i) = L;
}

// ---------------- fp32 -> single fp16 (weights) ----------------
__global__ __launch_bounds__(256) void k_cvt_w(const float* __restrict__ s,
    u16* __restrict__ d, int n){
  int i = (blockIdx.x * 256 + threadIdx.x) * 8;
  if (i >= n) return;
  float4 a = *(const float4*)(s + i);
  float4 b = *(const float4*)(s + i + 4);
  float vv[8] = {a.x, a.y, a.z, a.w, b.x, b.y, b.z, b.w};
  uint4 o;
  u32 w[8];
  #pragma unroll
  for (int j = 0; j < 8; j++) w[j] = f2h_bits(vv[j]);
  o.x = w[0] | (w[1] << 16); o.y = w[2] | (w[3] << 16);
  o.z = w[4] | (w[5] << 16); o.w = w[6] | (w[7] << 16);
  *(uint4*)(d + i) = o;
}

// ---------------- router (fp32 exact) ----------------
__global__ __launch_bounds__(256) void k_router(const float* __restrict__ x, const float* __restrict__ gw,
    float* __restrict__ probs, int* __restrict__ topidx, float* __restrict__ topw, int* __restrict__ counts){
  __shared__ float gs[NE * ND];
  int tid = threadIdx.x;
  for (int i = tid * 4; i < NE * ND; i += 1024) *(float4*)(gs + i) = *(const float4*)(gw + i);
  __syncthreads();
  int lane = tid & 63, wv = tid >> 6;
  int t = blockIdx.x * 4 + wv;
  const float* xr = x + (size_t)t * ND;
  float xv[16];
  #pragma unroll
  for (int i = 0; i < 16; i++) xv[i] = xr[lane + 64 * i];
  float lg[8];
  #pragma unroll
  for (int e = 0; e < 8; e++){
    float p = 0.f;
    #pragma unroll
    for (int i = 0; i < 16; i++) p += xv[i] * gs[e * ND + lane + 64 * i];
    #pragma unroll
    for (int off = 1; off < 64; off <<= 1) p += __shfl_xor(p, off, 64);
    lg[e] = p;
  }
  if (lane == 0){
    float m = lg[0];
    #pragma unroll
    for (int e = 1; e < 8; e++) m = fmaxf(m, lg[e]);
    float pr[8], ssum = 0.f;
    #pragma unroll
    for (int e = 0; e < 8; e++){ pr[e] = __expf(lg[e] - m); ssum += pr[e]; }
    float inv = 1.f / ssum;
    #pragma unroll
    for (int e = 0; e < 8; e++){ pr[e] *= inv; probs[(size_t)t * 8 + e] = pr[e]; }
    int i1 = 0;
    #pragma unroll
    for (int e = 1; e < 8; e++) if (lg[e] > lg[i1]) i1 = e;
    int i2 = (i1 == 0) ? 1 : 0;
    #pragma unroll
    for (int e = 0; e < 8; e++) if (e != i1 && lg[e] > lg[i2]) i2 = e;
    float wsum = pr[i1] + pr[i2];
    topidx[t * 2 + 0] = i1; topw[t * 2 + 0] = pr[i1] / wsum;
    topidx[t * 2 + 1] = i2; topw[t * 2 + 1] = pr[i2] / wsum;
    atomicAdd(&counts[i1], 1); atomicAdd(&counts[i2], 1);
  }
}

__global__ void k_fill(int* __restrict__ ltok){
  ltok[blockIdx.x * 256 + threadIdx.x] = -1;
}

// ctrl: [0..7]=counts [8..15]=cursors [16..24]=padded_off [32..32+NTILES)=tile_expert
__global__ __launch_bounds__(256) void k_offsets(int* __restrict__ ctrl){
  __shared__ int po[9];
  if (threadIdx.x == 0){
    int off = 0;
    #pragma unroll
    for (int e = 0; e < 8; e++){
      ctrl[16 + e] = off; po[e] = off;
      off += (ctrl[e] + 127) & ~127;
    }
    ctrl[24] = off; po[8] = off;
  }
  __syncthreads();
  for (int i = threadIdx.x; i < NTILES; i += 256){
    int rowb = i * 128;
    int e = -1;
    #pragma unroll
    for (int k = 0; k < 8; k++) if (rowb >= po[k] && rowb < po[k + 1]) e = k;
    ctrl[32 + i] = e;
  }
}

__global__ __launch_bounds__(256) void k_scatter(const int* __restrict__ topidx, const float* __restrict__ topw,
    int* __restrict__ ctrl, int* __restrict__ ltok, float* __restrict__ lwv){
  int t = blockIdx.x * 256 + threadIdx.x;
  #pragma unroll
  for (int k = 0; k < 2; k++){
    int e = topidx[t * 2 + k];
    int pos = atomicAdd(&ctrl[8 + e], 1);
    int idx = ctrl[16 + e] + pos;
    ltok[idx] = t; lwv[idx] = topw[t * 2 + k];
  }
}

// ---------------- C1: H = silu(X·W1^T) * (X·W3^T) ----------------
// fp16: A = x hi/lo (2-term), B = w1/w3 single (1-term). 4 waves 2x2,
// block tile 128(m) x 128(f), BK=32. All staging via global_load_lds with
// XOR-fold swizzle on the per-lane global source; LDS dest stays linear.
__global__ __launch_bounds__(256, 2) void k_mlp1(
    const u16* __restrict__ xh, const u16* __restrict__ xl,
    const u16* __restrict__ w1, const u16* __restrict__ w3,
    const int* __restrict__ ltok, const int* __restrict__ tile_expert,
    u16* __restrict__ H, int tile0)
{
  const int bx = blockIdx.x;
  const int e = tile_expert[tile0 + bx];
  if (e < 0) return;
  const int tid = threadIdx.x;
  const int lane = tid & 63, wid = tid >> 6;
  const int wm = wid >> 1, wn = wid & 1;
  const int r = lane & 31, half = lane >> 5;
  const int f0 = blockIdx.y * 128;

  __shared__ alignas(16) u16 sA[2][2][128 * BK];  // [buf][hi|lo]
  __shared__ alignas(16) u16 sB[2][2][128 * BK];  // [buf][w1|w3]
  __shared__ int sm_tok[128];

  if (tid < 128) sm_tok[tid] = ltok[(tile0 + bx) * 128 + tid];
  __syncthreads();

  // staging slots: each wave fills bands {wid, wid+4} of each 512-slot tile
  const int s0 = wid * 64 + lane, s1 = s0 + 256;
  const int S0 = swz(s0), S1 = swz(s1);
  const int r0 = S0 >> 2, g0 = S0 & 3;
  const int r1 = S1 >> 2, g1 = S1 & 3;
  int tk0 = sm_tok[r0]; if (tk0 < 0) tk0 = 0;
  int tk1 = sm_tok[r1]; if (tk1 < 0) tk1 = 0;
  const u16* pAh0 = xh + (size_t)tk0 * ND + g0 * 8;
  const u16* pAh1 = xh + (size_t)tk1 * ND + g1 * 8;
  const u16* pAl0 = xl + (size_t)tk0 * ND + g0 * 8;
  const u16* pAl1 = xl + (size_t)tk1 * ND + g1 * 8;
  const size_t wb = (size_t)e * NF + f0;
  const u16* pB10 = w1 + (wb + r0) * ND + g0 * 8;
  const u16* pB11 = w1 + (wb + r1) * ND + g1 * 8;
  const u16* pB30 = w3 + (wb + r0) * ND + g0 * 8;
  const u16* pB31 = w3 + (wb + r1) * ND + g1 * 8;
  const int dst0 = wid * 1024, dst1 = dst0 + 4096;

  // ds_read byte offsets (loop-invariant)
  int offA[2][2], offB[2][2];
  #pragma unroll
  for (int p = 0; p < 2; p++)
    #pragma unroll
    for (int ks = 0; ks < 2; ks++){
      int row = wm * 64 + p * 32 + r;
      offA[p][ks] = swz(row * 4 + ks * 2 + half) * 16;
    }
  #pragma unroll
  for (int q = 0; q < 2; q++)
    #pragma unroll
    for (int ks = 0; ks < 2; ks++){
      int row = wn * 64 + q * 32 + r;
      offB[q][ks] = swz(row * 4 + ks * 2 + half) * 16;
    }

#define ST1(nb, kt) { const size_t ko = (size_t)(kt) * BK; \
  GLD_LDS((char*)&sA[nb][0][0] + dst0, pAh0 + ko); \
  GLD_LDS((char*)&sA[nb][0][0] + dst1, pAh1 + ko); \
  GLD_LDS((char*)&sA[nb][1][0] + dst0, pAl0 + ko); \
  GLD_LDS((char*)&sA[nb][1][0] + dst1, pAl1 + ko); \
  GLD_LDS((char*)&sB[nb][0][0] + dst0, pB10 + ko); \
  GLD_LDS((char*)&sB[nb][0][0] + dst1, pB11 + ko); \
  GLD_LDS((char*)&sB[nb][1][0] + dst0, pB30 + ko); \
  GLD_LDS((char*)&sB[nb][1][0] + dst1, pB31 + ko); }

  ST1(0, 0);

  f32x16 acc1[2][2], acc3[2][2];
  #pragma unroll
  for (int p = 0; p < 2; p++)
    #pragma unroll
    for (int q = 0; q < 2; q++)
      #pragma unroll
      for (int j = 0; j < 16; j++){ acc1[p][q][j] = 0.f; acc3[p][q][j] = 0.f; }

  __syncthreads();

  int cb = 0;
  const int NK = ND / BK;
  for (int kt = 0; kt < NK; ++kt){
    const int nb = cb ^ 1;
    if (kt + 1 < NK) ST1(nb, kt + 1);
    const char* Ah = (const char*)&sA[cb][0][0];
    const char* Al = (const char*)&sA[cb][1][0];
    const char* B1 = (const char*)&sB[cb][0][0];
    const char* B3 = (const char*)&sB[cb][1][0];
    #pragma unroll
    for (int ks = 0; ks < 2; ks++){
      f16x8 ah[2], al[2], b1[2], b3[2];
      #pragma unroll
      for (int p = 0; p < 2; p++){
        ah[p] = *(const f16x8*)(Ah + offA[p][ks]);
        al[p] = *(const f16x8*)(Al + offA[p][ks]);
      }
      #pragma unroll
      for (int q = 0; q < 2; q++){
        b1[q] = *(const f16x8*)(B1 + offB[q][ks]);
        b3[q] = *(const f16x8*)(B3 + offB[q][ks]);
      }
      #pragma unroll
      for (int p = 0; p < 2; p++)
        #pragma unroll
        for (int q = 0; q < 2; q++){
          acc1[p][q] = MFMA(ah[p], b1[q], acc1[p][q]);
          acc1[p][q] = MFMA(al[p], b1[q], acc1[p][q]);
          acc3[p][q] = MFMA(ah[p], b3[q], acc3[p][q]);
          acc3[p][q] = MFMA(al[p], b3[q], acc3[p][q]);
        }
    }
    __syncthreads();
    cb = nb;
  }

  // epilogue: h = silu(s1)*s3 -> single fp16, plain row-major H
  const int hb = bx * 128;
  #pragma unroll
  for (int p = 0; p < 2; p++)
    #pragma unroll
    for (int q = 0; q < 2; q++)
      #pragma unroll
      for (int j = 0; j < 16; j++){
        const int rl = wm * 64 + p * 32 + (j & 3) + 8 * (j >> 2) + 4 * half;
        const int fc = f0 + wn * 64 + q * 32 + r;
        const float s1 = acc1[p][q][j];
        const float s3 = acc3[p][q][j];
        const float h = s1 * (1.f / (1.f + __expf(-s1))) * s3;
        H[(size_t)(hb + rl) * NF + fc] = f2h_bits(h);
      }
}

// ---------------- C2: out += w * (H · W2^T), single-term fp16 ----------------
// 4 waves 2x2 over 128(m) x 256(d), BK=32.
__global__ __launch_bounds__(256, 2) void k_mlp2(
    const u16* __restrict__ H, const u16* __restrict__ w2,
    const int* __restrict__ ltok, const float* __restrict__ lw,
    const int* __restrict__ tile_expert,
    float* __restrict__ out, int tile0)
{
  const int bx = blockIdx.x;
  const int e = tile_expert[tile0 + bx];
  if (e < 0) return;
  const int tid = threadIdx.x;
  const int lane = tid & 63, wid = tid >> 6;
  const int wm = wid >> 1, wn = wid & 1;
  const int r = lane & 31, half = lane >> 5;
  const int d0 = blockIdx.y * 256;
  const int hb = bx * 128;

  __shared__ alignas(16) u16 sA[2][128 * BK];   // 8 KB each
  __shared__ alignas(16) u16 sB[2][256 * BK];   // 16 KB each
  __shared__ int sm_tok[128];
  __shared__ float sm_wt[128];

  if (tid < 128){
    sm_tok[tid] = ltok[(tile0 + bx) * 128 + tid];
    sm_wt[tid]  = lw[(tile0 + bx) * 128 + tid];
  }

  // A staging: 512 slots, bands {wid, wid+4}
  const int sa0 = wid * 64 + lane, sa1 = sa0 + 256;
  const int SA0 = swz(sa0), SA1 = swz(sa1);
  const u16* pA0 = H + (size_t)(hb + (SA0 >> 2)) * NF + (SA0 & 3) * 8;
  const u16* pA1 = H + (size_t)(hb + (SA1 >> 2)) * NF + (SA1 & 3) * 8;
  const int dstA0 = wid * 1024, dstA1 = dstA0 + 4096;
  // B staging: 1024 slots, bands {wid, wid+4, wid+8, wid+12}
  const u16* pB[4];
  int dstB[4];
  #pragma unroll
  for (int c = 0; c < 4; c++){
    int s = wid * 64 + lane + c * 256;
    int S = swz(s);
    pB[c] = w2 + ((size_t)e * ND + d0 + (S >> 2)) * NF + (S & 3) * 8;
    dstB[c] = wid * 1024 + c * 4096;
  }

  int offA[2][2], offB[4][2];
  #pragma unroll
  for (int p = 0; p < 2; p++)
    #pragma unroll
    for (int ks = 0; ks < 2; ks++){
      int row = wm * 64 + p * 32 + r;
      offA[p][ks] = swz(row * 4 + ks * 2 + half) * 16;
    }
  #pragma unroll
  for (int q = 0; q < 4; q++)
    #pragma unroll
    for (int ks = 0; ks < 2; ks++){
      int row = wn * 128 + q * 32 + r;
      offB[q][ks] = swz(row * 4 + ks * 2 + half) * 16;
    }

#define ST2(nb, kt) { const size_t ko = (size_t)(kt) * BK; \
  GLD_LDS((char*)&sA[nb][0] + dstA0, pA0 + ko); \
  GLD_LDS((char*)&sA[nb][0] + dstA1, pA1 + ko); \
  GLD_LDS((char*)&sB[nb][0] + dstB[0], pB[0] + ko); \
  GLD_LDS((char*)&sB[nb][0] + dstB[1], pB[1] + ko); \
  GLD_LDS((char*)&sB[nb][0] + dstB[2], pB[2] + ko); \
  GLD_LDS((char*)&sB[nb][0] + dstB[3], pB[3] + ko); }

  ST2(0, 0);

  f32x16 acc[2][4];
  #pragma unroll
  for (int p = 0; p < 2; p++)
    #pragma unroll
    for (int q = 0; q < 4; q++)
      #pragma unroll
      for (int j = 0; j < 16; j++) acc[p][q][j] = 0.f;

  __syncthreads();

  int cb = 0;
  const int NK = NF / BK;
  for (int kt = 0; kt < NK; ++kt){
    const int nb = cb ^ 1;
    if (kt + 1 < NK) ST2(nb, kt + 1);
    const char* A = (const char*)&sA[cb][0];
    const char* B = (const char*)&sB[cb][0];
    #pragma unroll
    for (int ks = 0; ks < 2; ks++){
      f16x8 a[2], b[4];
      #pragma unroll
      for (int p = 0; p < 2; p++) a[p] = *(const f16x8*)(A + offA[p][ks]);
      #pragma unroll
      for (int q = 0; q < 4; q++) b[q] = *(const f16x8*)(B + offB[q][ks]);
      #pragma unroll
      for (int p = 0; p < 2; p++)
        #pragma unroll
        for (int q = 0; q < 4; q++)
          acc[p][q] = MFMA(a[p], b[q], acc[p][q]);
    }
    __syncthreads();
    cb = nb;
  }

  #pragma unroll
  for (int p = 0; p < 2; p++)
    #pragma unroll
    for (int q = 0; q < 4; q++)
      #pragma unroll
      for (int j = 0; j < 16; j++){
        const int rl = wm * 64 + p * 32 + (j & 3) + 8 * (j >> 2) + 4 * half;
        const int tok = sm_tok[rl];
        if (tok >= 0){
          const int d = d0 + wn * 128 + q * 32 + r;
          atomicAdd(out + (size_t)tok * ND + d, sm_wt[rl] * acc[p][q][j]);
        }
      }
}

// ---------------- host ----------------
extern "C" void kernel_launch(void* const* d_in, const int* in_sizes, int n_in,
                              void* d_out, int out_size, void* d_ws, size_t ws_size,
                              hipStream_t stream)
{
  (void)in_sizes; (void)n_in;
  const float* x  = (const float*)d_in[0];
  const float* gw = (const float*)d_in[1];
  const float* w1 = (const float*)d_in[2];
  const float* w3 = (const float*)d_in[3];
  const float* w2 = (const float*)d_in[4];
  float* out = (float*)d_out;
  char* ws = (char*)d_ws;

  size_t o = 0;
  int* ctrl = (int*)ws;                         o += 4096;
  int* topidx = (int*)(ws + o);                 o += (size_t)NT * 2 * 4;
  float* topw = (float*)(ws + o);               o += (size_t)NT * 2 * 4;
  int* ltok = (int*)(ws + o);                   o += (size_t)NTILES * 128 * 4;
  float* lwv = (float*)(ws + o);                o += (size_t)NTILES * 128 * 4;
  o = (o + 1023) & ~(size_t)1023;
  u16* xh = (u16*)(ws + o);  o += (size_t)NT * ND * 2;
  u16* xl = (u16*)(ws + o);  o += (size_t)NT * ND * 2;
  u16* w1f = (u16*)(ws + o); o += (size_t)NE * NF * ND * 2;
  u16* w3f = (u16*)(ws + o); o += (size_t)NE * NF * ND * 2;
  u16* w2f = (u16*)(ws + o); o += (size_t)NE * ND * NF * 2;

  size_t avail = (ws_size > o) ? (ws_size - o) : 0;
  int tiles_cap = (int)(avail / ((size_t)128 * NF * 2));
  if (tiles_cap < 1) tiles_cap = 1;
  int tps = (tiles_cap < NTILES) ? tiles_cap : NTILES;
  int nslabs = (NTILES + tps - 1) / tps;
  u16* Hbuf = (u16*)(ws + o);

  hipMemsetAsync(d_out, 0, (size_t)out_size * 4, stream);
  hipMemsetAsync(ctrl, 0, 4096, stream);

  const int nx = NT * ND;
  const int nw = NE * NF * ND;
  k_split_x<<<nx / 1024, 256, 0, stream>>>(x, xh, xl, nx);
  k_cvt_w<<<nw / 2048, 256, 0, stream>>>(w1, w1f, nw);
  k_cvt_w<<<nw / 2048, 256, 0, stream>>>(w3, w3f, nw);
  k_cvt_w<<<nw / 2048, 256, 0, stream>>>(w2, w2f, nw);
  k_router<<<NT / 4, 256, 0, stream>>>(x, gw, out + OUT_ELEMS, topidx, topw, ctrl);
  k_fill<<<(NTILES * 128) / 256, 256, 0, stream>>>(ltok);
  k_offsets<<<1, 256, 0, stream>>>(ctrl);
  k_scatter<<<NT / 256, 256, 0, stream>>>(topidx, topw, ctrl, ltok, lwv);

  for (int s = 0; s < nslabs; ++s){
    int tile0 = s * tps;
    int nt = NTILES - tile0; if (nt > tps) nt = tps;
    k_mlp1<<<dim3(nt, NF / 128), 256, 0, stream>>>(xh, xl, w1f, w3f,
                                                   ltok, ctrl + 32, Hbuf, tile0);
    k_mlp2<<<dim3(nt, ND / 256), 256, 0, stream>>>(Hbuf, w2f,
                                                   ltok, lwv, ctrl + 32, out, tile0);
  }
}